// Round 1
// baseline (1753.246 us; speedup 1.0000x reference)
//
#include <hip/hip_runtime.h>
#include <hip/hip_bf16.h>

#define NE 8
#define NT 512
#define DIN 7168
#define DINT 2048

typedef __bf16 bf16x8 __attribute__((ext_vector_type(8)));
typedef float f32x4 __attribute__((ext_vector_type(4)));
typedef unsigned short ushort8v __attribute__((ext_vector_type(8)));

__device__ __forceinline__ unsigned short f2bf(float f) {
    unsigned int u = __builtin_bit_cast(unsigned int, f);
    u += 0x7fffu + ((u >> 16) & 1u);
    return (unsigned short)(u >> 16);
}

// XOR swizzle: 16B granule within a 128B row is XOR'd with row&7.
// row stride = 64 bf16 elements (128B). k in elements (bf16).
__device__ __forceinline__ int swz(int row, int k) {
    return (row << 6) + (((k >> 3) ^ (row & 7)) << 3) + (k & 7);
}

// ---------------- Kernel A: h1 = x@w1^T + b1 ; h3 = x@w3^T + b3 ;
//                  g = silu(h1)*h3 -> bf16 in ws ----------------
__global__ __launch_bounds__(256, 2) void ffn_gate_up(
    const float* __restrict__ x, const float* __restrict__ w1,
    const float* __restrict__ b1, const float* __restrict__ w3,
    const float* __restrict__ b3, unsigned short* __restrict__ g) {
    __shared__ unsigned short As[128 * 64];
    __shared__ unsigned short B1s[128 * 64];
    __shared__ unsigned short B3s[128 * 64];

    const int tid = threadIdx.x;
    const int lane = tid & 63;
    const int wave = tid >> 6;
    const int wm = wave >> 1, wn = wave & 1;
    const int e = blockIdx.z;
    const int bm = blockIdx.x * 128;  // token offset
    const int bn = blockIdx.y * 128;  // inter-channel offset

    const float* xA = x + (size_t)e * NT * DIN + (size_t)bm * DIN;
    const float* w1B = w1 + (size_t)e * DINT * DIN + (size_t)bn * DIN;
    const float* w3B = w3 + (size_t)e * DINT * DIN + (size_t)bn * DIN;

    f32x4 acc1[4][4], acc3[4][4];
#pragma unroll
    for (int m = 0; m < 4; ++m)
#pragma unroll
        for (int n = 0; n < 4; ++n) {
            acc1[m][n] = (f32x4)0.0f;
            acc3[m][n] = (f32x4)0.0f;
        }

    const int srow = tid >> 4;        // 0..15, +16 per pass
    const int sk = (tid & 15) * 4;    // 0..60

    for (int kk = 0; kk < DIN; kk += 64) {
#pragma unroll
        for (int p = 0; p < 8; ++p) {
            const int row = p * 16 + srow;
            const float4 va = *(const float4*)(xA + (size_t)row * DIN + kk + sk);
            const float4 v1 = *(const float4*)(w1B + (size_t)row * DIN + kk + sk);
            const float4 v3 = *(const float4*)(w3B + (size_t)row * DIN + kk + sk);
            const int idx = swz(row, sk);
            ushort4 ha, h1v, h3v;
            ha.x = f2bf(va.x); ha.y = f2bf(va.y); ha.z = f2bf(va.z); ha.w = f2bf(va.w);
            h1v.x = f2bf(v1.x); h1v.y = f2bf(v1.y); h1v.z = f2bf(v1.z); h1v.w = f2bf(v1.w);
            h3v.x = f2bf(v3.x); h3v.y = f2bf(v3.y); h3v.z = f2bf(v3.z); h3v.w = f2bf(v3.w);
            *(ushort4*)&As[idx] = ha;
            *(ushort4*)&B1s[idx] = h1v;
            *(ushort4*)&B3s[idx] = h3v;
        }
        __syncthreads();
#pragma unroll
        for (int ks = 0; ks < 2; ++ks) {
            bf16x8 af[4], b1f[4], b3f[4];
            const int kf = ks * 32 + ((lane >> 4) << 3);
#pragma unroll
            for (int m = 0; m < 4; ++m) {
                const int row = wm * 64 + m * 16 + (lane & 15);
                af[m] = *(const bf16x8*)&As[swz(row, kf)];
            }
#pragma unroll
            for (int n = 0; n < 4; ++n) {
                const int row = wn * 64 + n * 16 + (lane & 15);
                b1f[n] = *(const bf16x8*)&B1s[swz(row, kf)];
                b3f[n] = *(const bf16x8*)&B3s[swz(row, kf)];
            }
#pragma unroll
            for (int m = 0; m < 4; ++m)
#pragma unroll
                for (int n = 0; n < 4; ++n) {
                    acc1[m][n] = __builtin_amdgcn_mfma_f32_16x16x32_bf16(af[m], b1f[n], acc1[m][n], 0, 0, 0);
                    acc3[m][n] = __builtin_amdgcn_mfma_f32_16x16x32_bf16(af[m], b3f[n], acc3[m][n], 0, 0, 0);
                }
        }
        __syncthreads();
    }

    // epilogue: bias + silu*mul -> bf16 g
    float bias1[4], bias3[4];
#pragma unroll
    for (int n = 0; n < 4; ++n) {
        const int f = bn + wn * 64 + n * 16 + (lane & 15);
        bias1[n] = b1[e * DINT + f];
        bias3[n] = b3[e * DINT + f];
    }
#pragma unroll
    for (int m = 0; m < 4; ++m)
#pragma unroll
        for (int n = 0; n < 4; ++n) {
            const int f = bn + wn * 64 + n * 16 + (lane & 15);
#pragma unroll
            for (int j = 0; j < 4; ++j) {
                const int t = bm + wm * 64 + m * 16 + ((lane >> 4) << 2) + j;
                const float h1 = acc1[m][n][j] + bias1[n];
                const float h3 = acc3[m][n][j] + bias3[n];
                const float sg = h1 / (1.0f + __expf(-h1));
                g[(size_t)e * NT * DINT + (size_t)t * DINT + f] = f2bf(sg * h3);
            }
        }
}

// ---------------- Kernel B: out = g@w2^T + b2 (fp32 out) ----------------
__global__ __launch_bounds__(256, 2) void ffn_down(
    const unsigned short* __restrict__ g, const float* __restrict__ w2,
    const float* __restrict__ b2, float* __restrict__ out) {
    __shared__ unsigned short As[128 * 64];
    __shared__ unsigned short Bs[128 * 64];

    const int tid = threadIdx.x;
    const int lane = tid & 63;
    const int wave = tid >> 6;
    const int wm = wave >> 1, wn = wave & 1;
    const int e = blockIdx.z;
    const int bm = blockIdx.x * 128;  // token offset
    const int bn = blockIdx.y * 128;  // out-channel offset

    const unsigned short* gA = g + (size_t)e * NT * DINT + (size_t)bm * DINT;
    const float* w2B = w2 + (size_t)e * DIN * DINT + (size_t)bn * DINT;

    f32x4 acc[4][4];
#pragma unroll
    for (int m = 0; m < 4; ++m)
#pragma unroll
        for (int n = 0; n < 4; ++n) acc[m][n] = (f32x4)0.0f;

    const int arow = tid >> 3;       // 0..31, +32 per pass (bf16 16B loads)
    const int ak = (tid & 7) * 8;    // 0..56
    const int brow = tid >> 4;       // 0..15, +16 per pass (f32 16B loads)
    const int bk = (tid & 15) * 4;   // 0..60

    for (int kk = 0; kk < DINT; kk += 64) {
#pragma unroll
        for (int p = 0; p < 4; ++p) {
            const int row = p * 32 + arow;
            const ushort8v v = *(const ushort8v*)(gA + (size_t)row * DINT + kk + ak);
            *(ushort8v*)&As[swz(row, ak)] = v;
        }
#pragma unroll
        for (int p = 0; p < 8; ++p) {
            const int row = p * 16 + brow;
            const float4 v = *(const float4*)(w2B + (size_t)row * DINT + kk + bk);
            ushort4 h;
            h.x = f2bf(v.x); h.y = f2bf(v.y); h.z = f2bf(v.z); h.w = f2bf(v.w);
            *(ushort4*)&Bs[swz(row, bk)] = h;
        }
        __syncthreads();
#pragma unroll
        for (int ks = 0; ks < 2; ++ks) {
            bf16x8 af[4], bf[4];
            const int kf = ks * 32 + ((lane >> 4) << 3);
#pragma unroll
            for (int m = 0; m < 4; ++m) {
                const int row = wm * 64 + m * 16 + (lane & 15);
                af[m] = *(const bf16x8*)&As[swz(row, kf)];
            }
#pragma unroll
            for (int n = 0; n < 4; ++n) {
                const int row = wn * 64 + n * 16 + (lane & 15);
                bf[n] = *(const bf16x8*)&Bs[swz(row, kf)];
            }
#pragma unroll
            for (int m = 0; m < 4; ++m)
#pragma unroll
                for (int n = 0; n < 4; ++n)
                    acc[m][n] = __builtin_amdgcn_mfma_f32_16x16x32_bf16(af[m], bf[n], acc[m][n], 0, 0, 0);
        }
        __syncthreads();
    }

    float bias[4];
#pragma unroll
    for (int n = 0; n < 4; ++n) {
        const int d = bn + wn * 64 + n * 16 + (lane & 15);
        bias[n] = b2[e * DIN + d];
    }
#pragma unroll
    for (int m = 0; m < 4; ++m)
#pragma unroll
        for (int n = 0; n < 4; ++n) {
            const int d = bn + wn * 64 + n * 16 + (lane & 15);
#pragma unroll
            for (int j = 0; j < 4; ++j) {
                const int t = bm + wm * 64 + m * 16 + ((lane >> 4) << 2) + j;
                out[(size_t)e * NT * DIN + (size_t)t * DIN + d] = acc[m][n][j] + bias[n];
            }
        }
}

extern "C" void kernel_launch(void* const* d_in, const int* in_sizes, int n_in,
                              void* d_out, int out_size, void* d_ws, size_t ws_size,
                              hipStream_t stream) {
    const float* x = (const float*)d_in[0];
    const float* w1 = (const float*)d_in[1];
    const float* b1 = (const float*)d_in[2];
    const float* w3 = (const float*)d_in[3];
    const float* b3 = (const float*)d_in[4];
    const float* w2 = (const float*)d_in[5];
    const float* b2 = (const float*)d_in[6];
    float* out = (float*)d_out;
    unsigned short* g = (unsigned short*)d_ws;  // [E][T][DINT] bf16, 16.8 MB

    dim3 gridA(NT / 128, DINT / 128, NE);  // 4,16,8 = 512 blocks
    dim3 gridB(NT / 128, DIN / 128, NE);   // 4,56,8 = 1792 blocks
    ffn_gate_up<<<gridA, dim3(256), 0, stream>>>(x, w1, b1, w3, b3, g);
    ffn_down<<<gridB, dim3(256), 0, stream>>>(g, w2, b2, out);
}

// Round 2
// 839.037 us; speedup vs baseline: 2.0896x; 2.0896x over previous
//
#include <hip/hip_runtime.h>
#include <hip/hip_bf16.h>

#define NE 8
#define NT 512
#define DIN 7168
#define DINT 2048
#define BK 64

typedef __bf16 bf16x8 __attribute__((ext_vector_type(8)));
typedef float f32x4 __attribute__((ext_vector_type(4)));
typedef unsigned short ushort8v __attribute__((ext_vector_type(8)));

// XOR swizzle: 16B granule within a 128B row XOR'd with row&7 (T2).
// row stride = 64 bf16 elements (128B).
__device__ __forceinline__ int swz(int row, int k) {
    return (row << 6) + (((k >> 3) ^ (row & 7)) << 3) + (k & 7);
}

__device__ __forceinline__ ushort4 cvt4(float4 v) {
    ushort4 h;
    h.x = __builtin_bit_cast(unsigned short, (__bf16)v.x);
    h.y = __builtin_bit_cast(unsigned short, (__bf16)v.y);
    h.z = __builtin_bit_cast(unsigned short, (__bf16)v.z);
    h.w = __builtin_bit_cast(unsigned short, (__bf16)v.w);
    return h;
}

// ---------------- Kernel A: gate+up, BM=64 (tokens) x BN=128 (F) ----------------
// grid (16, 8, 8) = 1024 blocks. Single-buffer LDS (40 KB) + register prefetch:
// loads for tile t+1 issued before the barrier; VGPR loads are NOT drained by
// __syncthreads, so they stay in flight across barrier + compute.
__global__ __launch_bounds__(256, 2) void ffn_gate_up(
    const float* __restrict__ x, const float* __restrict__ w1,
    const float* __restrict__ b1, const float* __restrict__ w3,
    const float* __restrict__ b3, unsigned short* __restrict__ g) {
    __shared__ unsigned short As[64 * BK];    // 8 KB
    __shared__ unsigned short B1s[128 * BK];  // 16 KB
    __shared__ unsigned short B3s[128 * BK];  // 16 KB

    const int tid = threadIdx.x;
    const int lane = tid & 63;
    const int wave = tid >> 6;
    const int wm = wave >> 1, wn = wave & 1;  // wave tile: 32 (M) x 64 (N)
    const int e = blockIdx.z;
    const int bn = blockIdx.x * 128;  // F offset
    const int bm = blockIdx.y * 64;   // token offset

    const float* xA = x + (size_t)e * NT * DIN + (size_t)bm * DIN;
    const float* w1B = w1 + (size_t)e * DINT * DIN + (size_t)bn * DIN;
    const float* w3B = w3 + (size_t)e * DINT * DIN + (size_t)bn * DIN;

    f32x4 acc1[2][4], acc3[2][4];
#pragma unroll
    for (int m = 0; m < 2; ++m)
#pragma unroll
        for (int n = 0; n < 4; ++n) {
            acc1[m][n] = (f32x4)0.0f;
            acc3[m][n] = (f32x4)0.0f;
        }

    const int srow = tid >> 4;        // 0..15
    const int scol = (tid & 15) * 4;  // 0..60

    float4 ra[4], rb1[8], rb3[8];

    // prologue: load tile 0 into regs
#pragma unroll
    for (int p = 0; p < 4; ++p)
        ra[p] = *(const float4*)(xA + (size_t)(p * 16 + srow) * DIN + scol);
#pragma unroll
    for (int p = 0; p < 8; ++p) {
        rb1[p] = *(const float4*)(w1B + (size_t)(p * 16 + srow) * DIN + scol);
        rb3[p] = *(const float4*)(w3B + (size_t)(p * 16 + srow) * DIN + scol);
    }

    for (int kk = 0; kk < DIN; kk += BK) {
        // write tile t (waits vmcnt for regs loaded one compute-phase ago)
#pragma unroll
        for (int p = 0; p < 4; ++p)
            *(ushort4*)&As[swz(p * 16 + srow, scol)] = cvt4(ra[p]);
#pragma unroll
        for (int p = 0; p < 8; ++p) {
            *(ushort4*)&B1s[swz(p * 16 + srow, scol)] = cvt4(rb1[p]);
            *(ushort4*)&B3s[swz(p * 16 + srow, scol)] = cvt4(rb3[p]);
        }
        // issue prefetch of tile t+1 (stays in flight across barrier+compute)
        if (kk + BK < DIN) {
            const int k2 = kk + BK;
#pragma unroll
            for (int p = 0; p < 4; ++p)
                ra[p] = *(const float4*)(xA + (size_t)(p * 16 + srow) * DIN + k2 + scol);
#pragma unroll
            for (int p = 0; p < 8; ++p) {
                rb1[p] = *(const float4*)(w1B + (size_t)(p * 16 + srow) * DIN + k2 + scol);
                rb3[p] = *(const float4*)(w3B + (size_t)(p * 16 + srow) * DIN + k2 + scol);
            }
        }
        __syncthreads();
#pragma unroll
        for (int ks = 0; ks < 2; ++ks) {
            bf16x8 af[2], b1f[4], b3f[4];
            const int kf = ks * 32 + ((lane >> 4) << 3);
#pragma unroll
            for (int m = 0; m < 2; ++m)
                af[m] = *(const bf16x8*)&As[swz(wm * 32 + m * 16 + (lane & 15), kf)];
#pragma unroll
            for (int n = 0; n < 4; ++n) {
                const int row = wn * 64 + n * 16 + (lane & 15);
                b1f[n] = *(const bf16x8*)&B1s[swz(row, kf)];
                b3f[n] = *(const bf16x8*)&B3s[swz(row, kf)];
            }
#pragma unroll
            for (int m = 0; m < 2; ++m)
#pragma unroll
                for (int n = 0; n < 4; ++n) {
                    acc1[m][n] = __builtin_amdgcn_mfma_f32_16x16x32_bf16(af[m], b1f[n], acc1[m][n], 0, 0, 0);
                    acc3[m][n] = __builtin_amdgcn_mfma_f32_16x16x32_bf16(af[m], b3f[n], acc3[m][n], 0, 0, 0);
                }
        }
        __syncthreads();
    }

    // epilogue: bias + silu*mul -> bf16 g
    float bias1[4], bias3[4];
#pragma unroll
    for (int n = 0; n < 4; ++n) {
        const int f = bn + wn * 64 + n * 16 + (lane & 15);
        bias1[n] = b1[e * DINT + f];
        bias3[n] = b3[e * DINT + f];
    }
#pragma unroll
    for (int m = 0; m < 2; ++m)
#pragma unroll
        for (int n = 0; n < 4; ++n) {
            const int f = bn + wn * 64 + n * 16 + (lane & 15);
#pragma unroll
            for (int j = 0; j < 4; ++j) {
                const int t = bm + wm * 32 + m * 16 + ((lane >> 4) << 2) + j;
                const float h1 = acc1[m][n][j] + bias1[n];
                const float h3 = acc3[m][n][j] + bias3[n];
                const float sg = h1 / (1.0f + __expf(-h1));
                g[(size_t)e * NT * DINT + (size_t)t * DINT + f] =
                    __builtin_bit_cast(unsigned short, (__bf16)(sg * h3));
            }
        }
}

// ---------------- Kernel B: down, BM=128 (tokens) x BN=128 (D) ----------------
// grid (56, 4, 8) = 1792 blocks. Same single-buffer + reg-prefetch structure.
__global__ __launch_bounds__(256, 2) void ffn_down(
    const unsigned short* __restrict__ g, const float* __restrict__ w2,
    const float* __restrict__ b2, float* __restrict__ out) {
    __shared__ unsigned short As[128 * BK];  // 16 KB
    __shared__ unsigned short Bs[128 * BK];  // 16 KB

    const int tid = threadIdx.x;
    const int lane = tid & 63;
    const int wave = tid >> 6;
    const int wm = wave >> 1, wn = wave & 1;  // wave tile: 64 x 64
    const int e = blockIdx.z;
    const int bn = blockIdx.x * 128;  // D offset
    const int bm = blockIdx.y * 128;  // token offset

    const unsigned short* gA = g + (size_t)e * NT * DINT + (size_t)bm * DINT;
    const float* w2B = w2 + (size_t)e * DIN * DINT + (size_t)bn * DINT;

    f32x4 acc[4][4];
#pragma unroll
    for (int m = 0; m < 4; ++m)
#pragma unroll
        for (int n = 0; n < 4; ++n) acc[m][n] = (f32x4)0.0f;

    const int arow = tid >> 3;        // 0..31
    const int acol = (tid & 7) * 8;   // 0..56 (bf16 elems, 16B chunks)
    const int brow = tid >> 4;        // 0..15
    const int bcol = (tid & 15) * 4;  // 0..60

    ushort8v ga[4];
    float4 rb[8];

#pragma unroll
    for (int p = 0; p < 4; ++p)
        ga[p] = *(const ushort8v*)(gA + (size_t)(p * 32 + arow) * DINT + acol);
#pragma unroll
    for (int p = 0; p < 8; ++p)
        rb[p] = *(const float4*)(w2B + (size_t)(p * 16 + brow) * DINT + bcol);

    for (int kk = 0; kk < DINT; kk += BK) {
#pragma unroll
        for (int p = 0; p < 4; ++p)
            *(ushort8v*)&As[swz(p * 32 + arow, acol)] = ga[p];
#pragma unroll
        for (int p = 0; p < 8; ++p)
            *(ushort4*)&Bs[swz(p * 16 + brow, bcol)] = cvt4(rb[p]);
        if (kk + BK < DINT) {
            const int k2 = kk + BK;
#pragma unroll
            for (int p = 0; p < 4; ++p)
                ga[p] = *(const ushort8v*)(gA + (size_t)(p * 32 + arow) * DINT + k2 + acol);
#pragma unroll
            for (int p = 0; p < 8; ++p)
                rb[p] = *(const float4*)(w2B + (size_t)(p * 16 + brow) * DINT + k2 + bcol);
        }
        __syncthreads();
#pragma unroll
        for (int ks = 0; ks < 2; ++ks) {
            bf16x8 af[4], bf[4];
            const int kf = ks * 32 + ((lane >> 4) << 3);
#pragma unroll
            for (int m = 0; m < 4; ++m)
                af[m] = *(const bf16x8*)&As[swz(wm * 64 + m * 16 + (lane & 15), kf)];
#pragma unroll
            for (int n = 0; n < 4; ++n)
                bf[n] = *(const bf16x8*)&Bs[swz(wn * 64 + n * 16 + (lane & 15), kf)];
#pragma unroll
            for (int m = 0; m < 4; ++m)
#pragma unroll
                for (int n = 0; n < 4; ++n)
                    acc[m][n] = __builtin_amdgcn_mfma_f32_16x16x32_bf16(af[m], bf[n], acc[m][n], 0, 0, 0);
        }
        __syncthreads();
    }

    float bias[4];
#pragma unroll
    for (int n = 0; n < 4; ++n) {
        const int d = bn + wn * 64 + n * 16 + (lane & 15);
        bias[n] = b2[e * DIN + d];
    }
#pragma unroll
    for (int m = 0; m < 4; ++m)
#pragma unroll
        for (int n = 0; n < 4; ++n) {
            const int d = bn + wn * 64 + n * 16 + (lane & 15);
#pragma unroll
            for (int j = 0; j < 4; ++j) {
                const int t = bm + wm * 64 + m * 16 + ((lane >> 4) << 2) + j;
                out[(size_t)e * NT * DIN + (size_t)t * DIN + d] = acc[m][n][j] + bias[n];
            }
        }
}

extern "C" void kernel_launch(void* const* d_in, const int* in_sizes, int n_in,
                              void* d_out, int out_size, void* d_ws, size_t ws_size,
                              hipStream_t stream) {
    const float* x = (const float*)d_in[0];
    const float* w1 = (const float*)d_in[1];
    const float* b1 = (const float*)d_in[2];
    const float* w3 = (const float*)d_in[3];
    const float* b3 = (const float*)d_in[4];
    const float* w2 = (const float*)d_in[5];
    const float* b2 = (const float*)d_in[6];
    float* out = (float*)d_out;
    unsigned short* g = (unsigned short*)d_ws;  // [E][T][DINT] bf16, 16.8 MB

    dim3 gridA(DINT / 128, NT / 64, NE);  // (16, 8, 8) = 1024 blocks
    dim3 gridB(DIN / 128, NT / 128, NE);  // (56, 4, 8) = 1792 blocks
    ffn_gate_up<<<gridA, dim3(256), 0, stream>>>(x, w1, b1, w3, b3, g);
    ffn_down<<<gridB, dim3(256), 0, stream>>>(g, w2, b2, out);
}

// Round 3
// 690.794 us; speedup vs baseline: 2.5380x; 1.2146x over previous
//
#include <hip/hip_runtime.h>
#include <hip/hip_bf16.h>

#define NE 8
#define NT 512
#define DIN 7168
#define DINT 2048
#define BK 64

typedef __bf16 bf16x8 __attribute__((ext_vector_type(8)));
typedef float f32x4 __attribute__((ext_vector_type(4)));
typedef unsigned short ushort8v __attribute__((ext_vector_type(8)));

// XOR swizzle (T2): 16B granule within a 128B row XOR'd with row&7.
// row stride = 64 bf16 elements (128B).
__device__ __forceinline__ int swz(int row, int k) {
    return (row << 6) + (((k >> 3) ^ (row & 7)) << 3) + (k & 7);
}

__device__ __forceinline__ ushort4 cvt4(float4 v) {
    ushort4 h;
    h.x = __builtin_bit_cast(unsigned short, (__bf16)v.x);
    h.y = __builtin_bit_cast(unsigned short, (__bf16)v.y);
    h.z = __builtin_bit_cast(unsigned short, (__bf16)v.z);
    h.w = __builtin_bit_cast(unsigned short, (__bf16)v.w);
    return h;
}

// ---------------- Kernel A: gate+up ----------------
// BM=256 (tokens) x BN=128 (F), BK=64, 512 threads = 8 waves (4 wm x 2 wn),
// wave-tile 64x64 with dual accumulators (h1, h3). grid (16,2,8)=256 blocks
// = exactly 1 per CU. Single-buffer LDS (64 KB) + register prefetch.
__global__ __launch_bounds__(512, 2) void ffn_gate_up(
    const float* __restrict__ x, const float* __restrict__ w1,
    const float* __restrict__ b1, const float* __restrict__ w3,
    const float* __restrict__ b3, unsigned short* __restrict__ g) {
    __shared__ unsigned short As[256 * BK];   // 32 KB
    __shared__ unsigned short B1s[128 * BK];  // 16 KB
    __shared__ unsigned short B3s[128 * BK];  // 16 KB

    const int tid = threadIdx.x;
    const int lane = tid & 63;
    const int wave = tid >> 6;                // 0..7
    const int wm = wave >> 1, wn = wave & 1;  // wave tile: 64 (M) x 64 (N)
    const int e = blockIdx.z;
    const int bn = blockIdx.x * 128;  // F offset
    const int bm = blockIdx.y * 256;  // token offset

    const float* xA = x + (size_t)e * NT * DIN + (size_t)bm * DIN;
    const float* w1B = w1 + (size_t)e * DINT * DIN + (size_t)bn * DIN;
    const float* w3B = w3 + (size_t)e * DINT * DIN + (size_t)bn * DIN;

    f32x4 acc1[4][4], acc3[4][4];  // 128 AGPR
#pragma unroll
    for (int m = 0; m < 4; ++m)
#pragma unroll
        for (int n = 0; n < 4; ++n) {
            acc1[m][n] = (f32x4)0.0f;
            acc3[m][n] = (f32x4)0.0f;
        }

    const int srow = tid >> 4;        // 0..31
    const int scol = (tid & 15) * 4;  // 0..60

    float4 ra[8], rb1[4], rb3[4];  // 64 VGPR in flight

    // prologue: load tile 0
#pragma unroll
    for (int p = 0; p < 8; ++p)
        ra[p] = *(const float4*)(xA + (size_t)(p * 32 + srow) * DIN + scol);
#pragma unroll
    for (int p = 0; p < 4; ++p) {
        rb1[p] = *(const float4*)(w1B + (size_t)(p * 32 + srow) * DIN + scol);
        rb3[p] = *(const float4*)(w3B + (size_t)(p * 32 + srow) * DIN + scol);
    }

    for (int kk = 0; kk < DIN; kk += BK) {
        // write tile t (vmcnt waits interleave per-register)
#pragma unroll
        for (int p = 0; p < 8; ++p)
            *(ushort4*)&As[swz(p * 32 + srow, scol)] = cvt4(ra[p]);
#pragma unroll
        for (int p = 0; p < 4; ++p) {
            *(ushort4*)&B1s[swz(p * 32 + srow, scol)] = cvt4(rb1[p]);
            *(ushort4*)&B3s[swz(p * 32 + srow, scol)] = cvt4(rb3[p]);
        }
        // prefetch tile t+1 (in flight across barrier + compute)
        if (kk + BK < DIN) {
            const int k2 = kk + BK;
#pragma unroll
            for (int p = 0; p < 8; ++p)
                ra[p] = *(const float4*)(xA + (size_t)(p * 32 + srow) * DIN + k2 + scol);
#pragma unroll
            for (int p = 0; p < 4; ++p) {
                rb1[p] = *(const float4*)(w1B + (size_t)(p * 32 + srow) * DIN + k2 + scol);
                rb3[p] = *(const float4*)(w3B + (size_t)(p * 32 + srow) * DIN + k2 + scol);
            }
        }
        __syncthreads();
#pragma unroll
        for (int ks = 0; ks < 2; ++ks) {
            const int kf = ks * 32 + ((lane >> 4) << 3);
            bf16x8 b1f[4], b3f[4];
#pragma unroll
            for (int n = 0; n < 4; ++n) {
                const int row = wn * 64 + n * 16 + (lane & 15);
                b1f[n] = *(const bf16x8*)&B1s[swz(row, kf)];
                b3f[n] = *(const bf16x8*)&B3s[swz(row, kf)];
            }
#pragma unroll
            for (int m = 0; m < 4; ++m) {
                const bf16x8 af = *(const bf16x8*)&As[swz(wm * 64 + m * 16 + (lane & 15), kf)];
#pragma unroll
                for (int n = 0; n < 4; ++n) {
                    acc1[m][n] = __builtin_amdgcn_mfma_f32_16x16x32_bf16(af, b1f[n], acc1[m][n], 0, 0, 0);
                    acc3[m][n] = __builtin_amdgcn_mfma_f32_16x16x32_bf16(af, b3f[n], acc3[m][n], 0, 0, 0);
                }
            }
        }
        __syncthreads();
    }

    // epilogue: bias + silu*mul -> bf16 g
    float bias1[4], bias3[4];
#pragma unroll
    for (int n = 0; n < 4; ++n) {
        const int f = bn + wn * 64 + n * 16 + (lane & 15);
        bias1[n] = b1[e * DINT + f];
        bias3[n] = b3[e * DINT + f];
    }
#pragma unroll
    for (int m = 0; m < 4; ++m)
#pragma unroll
        for (int n = 0; n < 4; ++n) {
            const int f = bn + wn * 64 + n * 16 + (lane & 15);
#pragma unroll
            for (int j = 0; j < 4; ++j) {
                const int t = bm + wm * 64 + m * 16 + ((lane >> 4) << 2) + j;
                const float h1 = acc1[m][n][j] + bias1[n];
                const float h3 = acc3[m][n][j] + bias3[n];
                const float sg = h1 / (1.0f + __expf(-h1));
                g[(size_t)e * NT * DINT + (size_t)t * DINT + f] =
                    __builtin_bit_cast(unsigned short, (__bf16)(sg * h3));
            }
        }
}

// ---------------- Kernel B: down ----------------
// BM=256 x BN=128, BK=64, 512 threads = 8 waves (4x2), wave-tile 64x64.
// grid (56,2,8) = 896 blocks.
__global__ __launch_bounds__(512, 2) void ffn_down(
    const unsigned short* __restrict__ g, const float* __restrict__ w2,
    const float* __restrict__ b2, float* __restrict__ out) {
    __shared__ unsigned short As[256 * BK];  // 32 KB (g, bf16)
    __shared__ unsigned short Bs[128 * BK];  // 16 KB (w2 -> bf16)

    const int tid = threadIdx.x;
    const int lane = tid & 63;
    const int wave = tid >> 6;
    const int wm = wave >> 1, wn = wave & 1;  // wave tile: 64 x 64
    const int e = blockIdx.z;
    const int bn = blockIdx.x * 128;  // D offset
    const int bm = blockIdx.y * 256;  // token offset

    const unsigned short* gA = g + (size_t)e * NT * DINT + (size_t)bm * DINT;
    const float* w2B = w2 + (size_t)e * DIN * DINT + (size_t)bn * DINT;

    f32x4 acc[4][4];  // 64 AGPR
#pragma unroll
    for (int m = 0; m < 4; ++m)
#pragma unroll
        for (int n = 0; n < 4; ++n) acc[m][n] = (f32x4)0.0f;

    const int arow = tid >> 3;        // 0..63
    const int acol = (tid & 7) * 8;   // 0..56 (bf16 elems, 16B chunks)
    const int brow = tid >> 4;        // 0..31
    const int bcol = (tid & 15) * 4;  // 0..60

    ushort8v ga[4];
    float4 rb[4];

#pragma unroll
    for (int p = 0; p < 4; ++p)
        ga[p] = *(const ushort8v*)(gA + (size_t)(p * 64 + arow) * DINT + acol);
#pragma unroll
    for (int p = 0; p < 4; ++p)
        rb[p] = *(const float4*)(w2B + (size_t)(p * 32 + brow) * DINT + bcol);

    for (int kk = 0; kk < DINT; kk += BK) {
#pragma unroll
        for (int p = 0; p < 4; ++p)
            *(ushort8v*)&As[swz(p * 64 + arow, acol)] = ga[p];
#pragma unroll
        for (int p = 0; p < 4; ++p)
            *(ushort4*)&Bs[swz(p * 32 + brow, bcol)] = cvt4(rb[p]);
        if (kk + BK < DINT) {
            const int k2 = kk + BK;
#pragma unroll
            for (int p = 0; p < 4; ++p)
                ga[p] = *(const ushort8v*)(gA + (size_t)(p * 64 + arow) * DINT + k2 + acol);
#pragma unroll
            for (int p = 0; p < 4; ++p)
                rb[p] = *(const float4*)(w2B + (size_t)(p * 32 + brow) * DINT + k2 + bcol);
        }
        __syncthreads();
#pragma unroll
        for (int ks = 0; ks < 2; ++ks) {
            const int kf = ks * 32 + ((lane >> 4) << 3);
            bf16x8 bf[4];
#pragma unroll
            for (int n = 0; n < 4; ++n)
                bf[n] = *(const bf16x8*)&Bs[swz(wn * 64 + n * 16 + (lane & 15), kf)];
#pragma unroll
            for (int m = 0; m < 4; ++m) {
                const bf16x8 af = *(const bf16x8*)&As[swz(wm * 64 + m * 16 + (lane & 15), kf)];
#pragma unroll
                for (int n = 0; n < 4; ++n)
                    acc[m][n] = __builtin_amdgcn_mfma_f32_16x16x32_bf16(af, bf[n], acc[m][n], 0, 0, 0);
            }
        }
        __syncthreads();
    }

    float bias[4];
#pragma unroll
    for (int n = 0; n < 4; ++n) {
        const int d = bn + wn * 64 + n * 16 + (lane & 15);
        bias[n] = b2[e * DIN + d];
    }
#pragma unroll
    for (int m = 0; m < 4; ++m)
#pragma unroll
        for (int n = 0; n < 4; ++n) {
            const int d = bn + wn * 64 + n * 16 + (lane & 15);
#pragma unroll
            for (int j = 0; j < 4; ++j) {
                const int t = bm + wm * 64 + m * 16 + ((lane >> 4) << 2) + j;
                out[(size_t)e * NT * DIN + (size_t)t * DIN + d] = acc[m][n][j] + bias[n];
            }
        }
}

extern "C" void kernel_launch(void* const* d_in, const int* in_sizes, int n_in,
                              void* d_out, int out_size, void* d_ws, size_t ws_size,
                              hipStream_t stream) {
    const float* x = (const float*)d_in[0];
    const float* w1 = (const float*)d_in[1];
    const float* b1 = (const float*)d_in[2];
    const float* w3 = (const float*)d_in[3];
    const float* b3 = (const float*)d_in[4];
    const float* w2 = (const float*)d_in[5];
    const float* b2 = (const float*)d_in[6];
    float* out = (float*)d_out;
    unsigned short* g = (unsigned short*)d_ws;  // [E][T][DINT] bf16, 16.8 MB

    dim3 gridA(DINT / 128, NT / 256, NE);  // (16, 2, 8) = 256 blocks
    dim3 gridB(DIN / 128, NT / 256, NE);   // (56, 2, 8) = 896 blocks
    ffn_gate_up<<<gridA, dim3(512), 0, stream>>>(x, w1, b1, w3, b3, g);
    ffn_down<<<gridB, dim3(512), 0, stream>>>(g, w2, b2, out);
}

// Round 4
// 578.025 us; speedup vs baseline: 3.0332x; 1.1951x over previous
//
#include <hip/hip_runtime.h>
#include <hip/hip_bf16.h>

#define NE 8
#define NT 512
#define DIN 7168
#define DINT 2048
#define BK 64

typedef __bf16 bf16x8 __attribute__((ext_vector_type(8)));
typedef float f32x4 __attribute__((ext_vector_type(4)));
typedef unsigned short ushort8v __attribute__((ext_vector_type(8)));

// XOR swizzle (T2): 16B granule within a 128B row XOR'd with row&7.
// row stride = 64 bf16 elements (128B).
__device__ __forceinline__ int swz(int row, int k) {
    return (row << 6) + (((k >> 3) ^ (row & 7)) << 3) + (k & 7);
}

__device__ __forceinline__ ushort4 cvt4(float4 v) {
    ushort4 h;
    h.x = __builtin_bit_cast(unsigned short, (__bf16)v.x);
    h.y = __builtin_bit_cast(unsigned short, (__bf16)v.y);
    h.z = __builtin_bit_cast(unsigned short, (__bf16)v.z);
    h.w = __builtin_bit_cast(unsigned short, (__bf16)v.w);
    return h;
}

// ---------------- Kernel A: gate+up ----------------
// BM=256 x BN=128, BK=64, 512 threads = 8 waves (4x2), wave-tile 64x64,
// dual acc. grid (16,2,8) = 256 blocks = 1/CU. Double-buffered LDS (128 KB),
// ONE barrier per iter; order: compute(buf[cur]) -> vmcnt-gated ds_writes
// (tile t+1) -> prefetch loads (tile t+2, clamped, branch-free) -> barrier.
__global__ __launch_bounds__(512, 2) void ffn_gate_up(
    const float* __restrict__ x, const float* __restrict__ w1,
    const float* __restrict__ b1, const float* __restrict__ w3,
    const float* __restrict__ b3, unsigned short* __restrict__ g) {
    __shared__ unsigned short As[2][256 * BK];   // 2x32 KB
    __shared__ unsigned short B1s[2][128 * BK];  // 2x16 KB
    __shared__ unsigned short B3s[2][128 * BK];  // 2x16 KB

    const int tid = threadIdx.x;
    const int lane = tid & 63;
    const int wave = tid >> 6;
    const int wm = wave >> 1, wn = wave & 1;  // wave tile 64(M) x 64(N)
    const int e = blockIdx.z;
    const int bn = blockIdx.x * 128;
    const int bm = blockIdx.y * 256;

    const float* xA = x + (size_t)e * NT * DIN + (size_t)bm * DIN;
    const float* w1B = w1 + (size_t)e * DINT * DIN + (size_t)bn * DIN;
    const float* w3B = w3 + (size_t)e * DINT * DIN + (size_t)bn * DIN;

    f32x4 acc1[4][4], acc3[4][4];
#pragma unroll
    for (int m = 0; m < 4; ++m)
#pragma unroll
        for (int n = 0; n < 4; ++n) {
            acc1[m][n] = (f32x4)0.0f;
            acc3[m][n] = (f32x4)0.0f;
        }

    const int srow = tid >> 4;        // 0..31
    const int scol = (tid & 15) * 4;  // 0..60

    float4 ra[8], rb1[4], rb3[4];

    // prologue: tile0 -> regs -> buf0 ; tile1 -> regs
#pragma unroll
    for (int p = 0; p < 8; ++p)
        ra[p] = *(const float4*)(xA + (size_t)(p * 32 + srow) * DIN + scol);
#pragma unroll
    for (int p = 0; p < 4; ++p) {
        rb1[p] = *(const float4*)(w1B + (size_t)(p * 32 + srow) * DIN + scol);
        rb3[p] = *(const float4*)(w3B + (size_t)(p * 32 + srow) * DIN + scol);
    }
#pragma unroll
    for (int p = 0; p < 8; ++p)
        *(ushort4*)&As[0][swz(p * 32 + srow, scol)] = cvt4(ra[p]);
#pragma unroll
    for (int p = 0; p < 4; ++p) {
        *(ushort4*)&B1s[0][swz(p * 32 + srow, scol)] = cvt4(rb1[p]);
        *(ushort4*)&B3s[0][swz(p * 32 + srow, scol)] = cvt4(rb3[p]);
    }
#pragma unroll
    for (int p = 0; p < 8; ++p)
        ra[p] = *(const float4*)(xA + (size_t)(p * 32 + srow) * DIN + BK + scol);
#pragma unroll
    for (int p = 0; p < 4; ++p) {
        rb1[p] = *(const float4*)(w1B + (size_t)(p * 32 + srow) * DIN + BK + scol);
        rb3[p] = *(const float4*)(w3B + (size_t)(p * 32 + srow) * DIN + BK + scol);
    }
    __syncthreads();

    int cur = 0;
    const int NIT = DIN / BK;  // 112
    for (int t = 0; t < NIT - 1; ++t) {
        // ---- compute tile t from buf[cur] ----
#pragma unroll
        for (int ks = 0; ks < 2; ++ks) {
            const int kf = ks * 32 + ((lane >> 4) << 3);
            bf16x8 b1f[4], b3f[4];
#pragma unroll
            for (int n = 0; n < 4; ++n) {
                const int row = wn * 64 + n * 16 + (lane & 15);
                b1f[n] = *(const bf16x8*)&B1s[cur][swz(row, kf)];
                b3f[n] = *(const bf16x8*)&B3s[cur][swz(row, kf)];
            }
#pragma unroll
            for (int m = 0; m < 4; ++m) {
                const bf16x8 af = *(const bf16x8*)&As[cur][swz(wm * 64 + m * 16 + (lane & 15), kf)];
#pragma unroll
                for (int n = 0; n < 4; ++n) {
                    acc1[m][n] = __builtin_amdgcn_mfma_f32_16x16x32_bf16(af, b1f[n], acc1[m][n], 0, 0, 0);
                    acc3[m][n] = __builtin_amdgcn_mfma_f32_16x16x32_bf16(af, b3f[n], acc3[m][n], 0, 0, 0);
                }
            }
        }
        // ---- stage tile t+1 -> buf[cur^1] (vmcnt-gated; loads issued iter t-1) ----
        const int nxt = cur ^ 1;
#pragma unroll
        for (int p = 0; p < 8; ++p)
            *(ushort4*)&As[nxt][swz(p * 32 + srow, scol)] = cvt4(ra[p]);
#pragma unroll
        for (int p = 0; p < 4; ++p) {
            *(ushort4*)&B1s[nxt][swz(p * 32 + srow, scol)] = cvt4(rb1[p]);
            *(ushort4*)&B3s[nxt][swz(p * 32 + srow, scol)] = cvt4(rb3[p]);
        }
        // ---- prefetch tile t+2 (clamped; keeps loop branch-free) ----
        const int kld = min((t + 2) * BK, DIN - BK);
#pragma unroll
        for (int p = 0; p < 8; ++p)
            ra[p] = *(const float4*)(xA + (size_t)(p * 32 + srow) * DIN + kld + scol);
#pragma unroll
        for (int p = 0; p < 4; ++p) {
            rb1[p] = *(const float4*)(w1B + (size_t)(p * 32 + srow) * DIN + kld + scol);
            rb3[p] = *(const float4*)(w3B + (size_t)(p * 32 + srow) * DIN + kld + scol);
        }
        __syncthreads();
        cur = nxt;
    }
    // ---- final tile ----
#pragma unroll
    for (int ks = 0; ks < 2; ++ks) {
        const int kf = ks * 32 + ((lane >> 4) << 3);
        bf16x8 b1f[4], b3f[4];
#pragma unroll
        for (int n = 0; n < 4; ++n) {
            const int row = wn * 64 + n * 16 + (lane & 15);
            b1f[n] = *(const bf16x8*)&B1s[cur][swz(row, kf)];
            b3f[n] = *(const bf16x8*)&B3s[cur][swz(row, kf)];
        }
#pragma unroll
        for (int m = 0; m < 4; ++m) {
            const bf16x8 af = *(const bf16x8*)&As[cur][swz(wm * 64 + m * 16 + (lane & 15), kf)];
#pragma unroll
            for (int n = 0; n < 4; ++n) {
                acc1[m][n] = __builtin_amdgcn_mfma_f32_16x16x32_bf16(af, b1f[n], acc1[m][n], 0, 0, 0);
                acc3[m][n] = __builtin_amdgcn_mfma_f32_16x16x32_bf16(af, b3f[n], acc3[m][n], 0, 0, 0);
            }
        }
    }

    // epilogue: bias + silu*mul -> bf16 g
    float bias1[4], bias3[4];
#pragma unroll
    for (int n = 0; n < 4; ++n) {
        const int f = bn + wn * 64 + n * 16 + (lane & 15);
        bias1[n] = b1[e * DINT + f];
        bias3[n] = b3[e * DINT + f];
    }
#pragma unroll
    for (int m = 0; m < 4; ++m)
#pragma unroll
        for (int n = 0; n < 4; ++n) {
            const int f = bn + wn * 64 + n * 16 + (lane & 15);
#pragma unroll
            for (int j = 0; j < 4; ++j) {
                const int t = bm + wm * 64 + m * 16 + ((lane >> 4) << 2) + j;
                const float h1 = acc1[m][n][j] + bias1[n];
                const float h3 = acc3[m][n][j] + bias3[n];
                const float sg = h1 / (1.0f + __expf(-h1));
                g[(size_t)e * NT * DINT + (size_t)t * DINT + f] =
                    __builtin_bit_cast(unsigned short, (__bf16)(sg * h3));
            }
        }
}

// ---------------- Kernel B: down ----------------
// BM=256 x BN=128, BK=64, 512 threads, wave-tile 64x64. grid (56,2,8)=896.
// Same dbuf structure; LDS 96 KB.
__global__ __launch_bounds__(512, 2) void ffn_down(
    const unsigned short* __restrict__ g, const float* __restrict__ w2,
    const float* __restrict__ b2, float* __restrict__ out) {
    __shared__ unsigned short As[2][256 * BK];  // 2x32 KB
    __shared__ unsigned short Bs[2][128 * BK];  // 2x16 KB

    const int tid = threadIdx.x;
    const int lane = tid & 63;
    const int wave = tid >> 6;
    const int wm = wave >> 1, wn = wave & 1;
    const int e = blockIdx.z;
    const int bn = blockIdx.x * 128;
    const int bm = blockIdx.y * 256;

    const unsigned short* gA = g + (size_t)e * NT * DINT + (size_t)bm * DINT;
    const float* w2B = w2 + (size_t)e * DIN * DINT + (size_t)bn * DINT;

    f32x4 acc[4][4];
#pragma unroll
    for (int m = 0; m < 4; ++m)
#pragma unroll
        for (int n = 0; n < 4; ++n) acc[m][n] = (f32x4)0.0f;

    const int arow = tid >> 3;        // 0..63
    const int acol = (tid & 7) * 8;   // bf16 elems
    const int brow = tid >> 4;        // 0..31
    const int bcol = (tid & 15) * 4;

    ushort8v ga[4];
    float4 rb[4];

#pragma unroll
    for (int p = 0; p < 4; ++p)
        ga[p] = *(const ushort8v*)(gA + (size_t)(p * 64 + arow) * DINT + acol);
#pragma unroll
    for (int p = 0; p < 4; ++p)
        rb[p] = *(const float4*)(w2B + (size_t)(p * 32 + brow) * DINT + bcol);
#pragma unroll
    for (int p = 0; p < 4; ++p)
        *(ushort8v*)&As[0][swz(p * 64 + arow, acol)] = ga[p];
#pragma unroll
    for (int p = 0; p < 4; ++p)
        *(ushort4*)&Bs[0][swz(p * 32 + brow, bcol)] = cvt4(rb[p]);
#pragma unroll
    for (int p = 0; p < 4; ++p)
        ga[p] = *(const ushort8v*)(gA + (size_t)(p * 64 + arow) * DINT + BK + acol);
#pragma unroll
    for (int p = 0; p < 4; ++p)
        rb[p] = *(const float4*)(w2B + (size_t)(p * 32 + brow) * DINT + BK + bcol);
    __syncthreads();

    int cur = 0;
    const int NIT = DINT / BK;  // 32
    for (int t = 0; t < NIT - 1; ++t) {
#pragma unroll
        for (int ks = 0; ks < 2; ++ks) {
            const int kf = ks * 32 + ((lane >> 4) << 3);
            bf16x8 bf[4];
#pragma unroll
            for (int n = 0; n < 4; ++n)
                bf[n] = *(const bf16x8*)&Bs[cur][swz(wn * 64 + n * 16 + (lane & 15), kf)];
#pragma unroll
            for (int m = 0; m < 4; ++m) {
                const bf16x8 af = *(const bf16x8*)&As[cur][swz(wm * 64 + m * 16 + (lane & 15), kf)];
#pragma unroll
                for (int n = 0; n < 4; ++n)
                    acc[m][n] = __builtin_amdgcn_mfma_f32_16x16x32_bf16(af, bf[n], acc[m][n], 0, 0, 0);
            }
        }
        const int nxt = cur ^ 1;
#pragma unroll
        for (int p = 0; p < 4; ++p)
            *(ushort8v*)&As[nxt][swz(p * 64 + arow, acol)] = ga[p];
#pragma unroll
        for (int p = 0; p < 4; ++p)
            *(ushort4*)&Bs[nxt][swz(p * 32 + brow, bcol)] = cvt4(rb[p]);
        const int kld = min((t + 2) * BK, DINT - BK);
#pragma unroll
        for (int p = 0; p < 4; ++p)
            ga[p] = *(const ushort8v*)(gA + (size_t)(p * 64 + arow) * DINT + kld + acol);
#pragma unroll
        for (int p = 0; p < 4; ++p)
            rb[p] = *(const float4*)(w2B + (size_t)(p * 32 + brow) * DINT + kld + bcol);
        __syncthreads();
        cur = nxt;
    }
#pragma unroll
    for (int ks = 0; ks < 2; ++ks) {
        const int kf = ks * 32 + ((lane >> 4) << 3);
        bf16x8 bf[4];
#pragma unroll
        for (int n = 0; n < 4; ++n)
            bf[n] = *(const bf16x8*)&Bs[cur][swz(wn * 64 + n * 16 + (lane & 15), kf)];
#pragma unroll
        for (int m = 0; m < 4; ++m) {
            const bf16x8 af = *(const bf16x8*)&As[cur][swz(wm * 64 + m * 16 + (lane & 15), kf)];
#pragma unroll
            for (int n = 0; n < 4; ++n)
                acc[m][n] = __builtin_amdgcn_mfma_f32_16x16x32_bf16(af, bf[n], acc[m][n], 0, 0, 0);
        }
    }

    float bias[4];
#pragma unroll
    for (int n = 0; n < 4; ++n) {
        const int d = bn + wn * 64 + n * 16 + (lane & 15);
        bias[n] = b2[e * DIN + d];
    }
#pragma unroll
    for (int m = 0; m < 4; ++m)
#pragma unroll
        for (int n = 0; n < 4; ++n) {
            const int d = bn + wn * 64 + n * 16 + (lane & 15);
#pragma unroll
            for (int j = 0; j < 4; ++j) {
                const int t = bm + wm * 64 + m * 16 + ((lane >> 4) << 2) + j;
                out[(size_t)e * NT * DIN + (size_t)t * DIN + d] = acc[m][n][j] + bias[n];
            }
        }
}

extern "C" void kernel_launch(void* const* d_in, const int* in_sizes, int n_in,
                              void* d_out, int out_size, void* d_ws, size_t ws_size,
                              hipStream_t stream) {
    const float* x = (const float*)d_in[0];
    const float* w1 = (const float*)d_in[1];
    const float* b1 = (const float*)d_in[2];
    const float* w3 = (const float*)d_in[3];
    const float* b3 = (const float*)d_in[4];
    const float* w2 = (const float*)d_in[5];
    const float* b2 = (const float*)d_in[6];
    float* out = (float*)d_out;
    unsigned short* g = (unsigned short*)d_ws;  // [E][T][DINT] bf16

    dim3 gridA(DINT / 128, NT / 256, NE);  // (16, 2, 8) = 256 blocks
    dim3 gridB(DIN / 128, NT / 256, NE);   // (56, 2, 8) = 896 blocks
    ffn_gate_up<<<gridA, dim3(512), 0, stream>>>(x, w1, b1, w3, b3, g);
    ffn_down<<<gridB, dim3(512), 0, stream>>>(g, w2, b2, out);
}